// Round 6
// baseline (275.821 us; speedup 1.0000x reference)
//
#include <hip/hip_runtime.h>
#include <stdint.h>

// Disable FP contraction file-wide: the d2 <= R2 inclusion test is a discrete
// decision that must match the reference's fp32 mul+add rounding.
#pragma clang fp contract(off)

#define S 256
#define NPTS 100000
#define BATCH 4
#define CCH 64
#define K 8

#define TILE 16                 // tile edge in pixels
#define TPB 16                  // tiles per batch edge (S/TILE)
#define NTILES (BATCH * TPB * TPB)
#define CAP 768                 // entries per tile list (center tile ~200 expected)

static constexpr float R2 = 0.01171875f * 0.01171875f;  // (1.5/256*2)^2, exact
static constexpr unsigned long long SENT = 0xFFFFFFFFFFFFFFFFULL;

// ---------------------------------------------------------------------------
// Kernel 1: bin points into per-tile candidate lists.
// One thread per (batch, point). A point's 4x4 pixel window overlaps at most
// 2x2 tiles of 16x16 px. Entry = float4(x, y, z, idx-as-float-bits).
// 32-bit global atomicAdd cursors only (proven pattern from R1-R3).
// ---------------------------------------------------------------------------
__global__ __launch_bounds__(256) void fill_kernel(
        const float* __restrict__ pts,
        int* __restrict__ counts,
        float4* __restrict__ entries) {
    int gid = blockIdx.x * blockDim.x + threadIdx.x;
    if (gid >= BATCH * NPTS) return;
    int b = gid / NPTS;
    int n = gid - b * NPTS;

    const float* p = pts + (size_t)gid * 3;
    float x = -p[0];                 // reference flips x,y signs
    float y = -p[1];
    float z = p[2];
    if (!(z >= 0.0f)) return;

    float px = (1.0f - x) * 128.0f - 0.5f;   // (1-x)*(S/2) - 0.5
    float py = (1.0f - y) * 128.0f - 0.5f;
    int cj0 = (int)floorf(px);
    int ci0 = (int)floorf(py);
    // window rows/cols: ci0-1 .. ci0+2
    if (ci0 + 2 < 0 || ci0 - 1 > S - 1 || cj0 + 2 < 0 || cj0 - 1 > S - 1) return;

    int ti_lo = (ci0 - 1 < 0 ? 0 : ci0 - 1) >> 4;
    int ti_hi = (ci0 + 2 > S - 1 ? S - 1 : ci0 + 2) >> 4;
    int tj_lo = (cj0 - 1 < 0 ? 0 : cj0 - 1) >> 4;
    int tj_hi = (cj0 + 2 > S - 1 ? S - 1 : cj0 + 2) >> 4;

    float4 v = make_float4(x, y, z, __int_as_float(n));
    for (int ti = ti_lo; ti <= ti_hi; ++ti) {
        for (int tj = tj_lo; tj <= tj_hi; ++tj) {
            int t = (b * TPB + ti) * TPB + tj;
            int pos = atomicAdd(&counts[t], 1);
            if (pos < CAP) entries[(size_t)t * CAP + pos] = v;
        }
    }
}

// ---------------------------------------------------------------------------
// Kernel 2: per-tile top-K + blend, NO ATOMICS. One block per 16x16 tile,
// 512 threads.
//   Stage:  cooperative load of the tile's entry list global->LDS.
//   Select: threads 0..255 each own one pixel; scan the entry list with
//           wave-uniform LDS broadcast reads; d2<=R2 implies the pixel is in
//           the point's 4x4 window (radius 1.5px vs window reach 2px, 0.5px
//           margin >> fp error), so the candidate set matches the reference;
//           branchless unrolled insertion sort keeps the K smallest
//           (z_bits<<32|idx) keys (+ d2) in registers = exact reference
//           lexsort order, deterministic. Then alpha/cumprod -> (idx, wgt)
//           pairs in LDS.
//   Blend:  8 waves; wave = 64 lanes = 64 channels, 2 rows of 16 px each;
//           k-major gather (16 independent loads in flight, wave-uniform idx
//           broadcast); store 16 contiguous w-floats per lane (4x float4).
// ---------------------------------------------------------------------------
__global__ __launch_bounds__(512) void tile_kernel(
        const float* __restrict__ feat,
        const int* __restrict__ counts,
        const float4* __restrict__ entries,
        float* __restrict__ out) {
    int tj = blockIdx.x;    // 0..15
    int ti = blockIdx.y;    // 0..15
    int b  = blockIdx.z;    // 0..3
    int tid = threadIdx.x;

    __shared__ float4 s_ent[CAP];
    __shared__ uint2  s_slots[TILE * TILE][K];
    __shared__ int    s_cnt[TILE * TILE];

    int t = (b * TPB + ti) * TPB + tj;
    int cnt = counts[t];
    if (cnt > CAP) cnt = CAP;
    const float4* elist = entries + (size_t)t * CAP;

    for (int i = tid; i < cnt; i += 512) s_ent[i] = elist[i];
    __syncthreads();

    if (tid < TILE * TILE) {
        int pi = tid;
        int h = ti * TILE + (pi >> 4);
        int w = tj * TILE + (pi & 15);
        float cy = 1.0f - 2.0f * ((float)h + 0.5f) / 256.0f;
        float cx = 1.0f - 2.0f * ((float)w + 0.5f) / 256.0f;

        unsigned long long topk[K];
        float topd2[K];
#pragma unroll
        for (int k = 0; k < K; ++k) { topk[k] = SENT; topd2[k] = 0.0f; }

        for (int e = 0; e < cnt; ++e) {
            float4 v = s_ent[e];                 // uniform addr -> broadcast
            float dy = cy - v.y;
            float dx = cx - v.x;
            float d2 = dy * dy + dx * dx;
            if (d2 <= R2) {
                unsigned long long key =
                    ((unsigned long long)__float_as_uint(v.z) << 32) |
                    (unsigned int)__float_as_int(v.w);
                if (key < topk[K - 1]) {
                    // branchless insertion (keys unique: include idx)
#pragma unroll
                    for (int k = K - 1; k >= 0; --k) {
                        unsigned long long cur = topk[k];
                        float curd = topd2[k];
                        bool prev_ge = (k > 0) && (topk[k - 1] > key);
                        bool cur_ge = (cur > key);
                        unsigned long long pk = (k > 0) ? topk[k - 1] : 0ULL;
                        float pd = (k > 0) ? topd2[k - 1] : 0.0f;
                        topk[k]  = prev_ge ? pk : (cur_ge ? key : cur);
                        topd2[k] = prev_ge ? pd : (cur_ge ? d2 : curd);
                    }
                }
            }
        }

        // weights: alpha from d2, exclusive cumprod of (1-alpha)
        float trans = 1.0f;
        int cnt_p = 0;
#pragma unroll
        for (int k = 0; k < K; ++k) {
            unsigned long long key = topk[k];
            float wgt = 0.0f;
            unsigned idx = 0;
            if (key != SENT) {
                idx = (unsigned)(key & 0xFFFFFFFFULL);
                float dist = topd2[k] / R2;
                dist = fminf(fmaxf(dist, 0.001f), 1.0f);
                float alpha = 1.0f - sqrtf(dist);   // gamma=1 -> **0.5
                wgt = alpha * trans;
                trans *= (1.0f - alpha);
                cnt_p = k + 1;
            }
            s_slots[pi][k] = make_uint2(idx, __float_as_uint(wgt));
        }
        s_cnt[pi] = cnt_p;
    }
    __syncthreads();

    // Blend: 8 waves; wave handles rows 2*wid and 2*wid+1.
    int wave = tid >> 6;
    int lane = tid & 63;    // channel
    const float* fbl = feat + (size_t)b * NPTS * CCH + lane;

    for (int rr = 0; rr < 2; ++rr) {
        int r = wave * 2 + rr;          // row within tile
        int pbase = r * TILE;           // 16 pixels of this row

        int kmax = 0;
#pragma unroll
        for (int i = 0; i < 16; ++i) {
            int c = s_cnt[pbase + i];
            kmax = c > kmax ? c : kmax;
        }

        float acc[16];
#pragma unroll
        for (int i = 0; i < 16; ++i) acc[i] = 0.0f;

        for (int k = 0; k < kmax; ++k) {
            float vv[16];
            float ww[16];
#pragma unroll
            for (int i = 0; i < 16; ++i) {
                uint2 u = s_slots[pbase + i][k];    // wave-uniform broadcast
                ww[i] = __uint_as_float(u.y);
                vv[i] = fbl[(size_t)u.x << 6];
            }
#pragma unroll
            for (int i = 0; i < 16; ++i) acc[i] += ww[i] * vv[i];
        }

        int h = ti * TILE + r;
        int w0 = tj * TILE;
        size_t obase = (((size_t)b * CCH + lane) * S + h) * S + w0;
        float4* o4 = (float4*)(out + obase);
#pragma unroll
        for (int q = 0; q < 4; ++q)
            o4[q] = make_float4(acc[4 * q + 0], acc[4 * q + 1],
                                acc[4 * q + 2], acc[4 * q + 3]);
    }
}

extern "C" void kernel_launch(void* const* d_in, const int* in_sizes, int n_in,
                              void* d_out, int out_size, void* d_ws, size_t ws_size,
                              hipStream_t stream) {
    const float* pts  = (const float*)d_in[0];
    const float* feat = (const float*)d_in[1];
    float* out = (float*)d_out;

    // ws layout: counts[NTILES] (4KB) | entries[NTILES*CAP] float4 (12.6MB)
    // total 12.59 MB -- under the 16.77 MB proven safe in rounds 1-3.
    int* counts = (int*)d_ws;
    float4* entries = (float4*)((char*)d_ws + 4096);

    hipMemsetAsync(counts, 0, NTILES * sizeof(int), stream);

    int total = BATCH * NPTS;
    fill_kernel<<<(total + 255) / 256, 256, 0, stream>>>(pts, counts, entries);

    dim3 grid(TPB, TPB, BATCH);
    tile_kernel<<<grid, 512, 0, stream>>>(feat, counts, entries, out);
}